// Round 17
// baseline (294.019 us; speedup 1.0000x reference)
//
#include <hip/hip_runtime.h>
#include <hip/hip_fp16.h>

#define NN 50000
#define NE 800000
#define NB_SCAN 196   // ceil(NN/256)
#define NB_HIST 3125  // NE/256 exactly
#define NB_CVT 25000  // NE*8/256 (thread = one float4 -> half4)

typedef _Float16 f16x8 __attribute__((ext_vector_type(8)));
typedef float f32x4 __attribute__((ext_vector_type(4)));
typedef unsigned long long u64;
union U4 { uint4 u; f16x8 f; __half2 h2[4]; };

__device__ inline f16x8 cvt8(float4 a0, float4 a1) {
  U4 u;
  u.h2[0] = __floats2half2_rn(a0.x, a0.y);
  u.h2[1] = __floats2half2_rn(a0.z, a0.w);
  u.h2[2] = __floats2half2_rn(a1.x, a1.y);
  u.h2[3] = __floats2half2_rn(a1.z, a1.w);
  return u.f;
}

// CSR slot encoding: e (20b) | s<<20 (17b) | d<<40 (17b)
__device__ inline int dec_e(u64 v) { return (int)(v & 0xFFFFFull); }
__device__ inline int dec_s(u64 v) { return (int)((v >> 20) & 0x1FFFFull); }
__device__ inline int dec_d(u64 v) { return (int)(v >> 40); }

// ---- workspace layout (4B units) ----
// deg i32[NN]@0 | agg_h0[2NN]@NN | agg_e f32[32NN]@3NN | agg_h1 f32[64NN]@35NN
// h1h f16(32NN units)@99NN | W1t@131NN(2304) bsums@131NN+30000
// offs@132NN fill@133NN | eslist u64[NE](32NN units)@134NN..166NN
// Pb f16@3NN (over agg_e, same-row RAW in lin2pq) ; Qb f16@99NN (over h1h)
// eah f16[NE*32](256NN units... = 12.8M floats)@227NN..483NN

// -------- CSR hist + folded W1 transpose + folded ea->f16 conversion --------
__global__ __launch_bounds__(256) void k_hist(const int* __restrict__ ei,
                                              int* __restrict__ deg,
                                              const float* __restrict__ W1,
                                              float* __restrict__ W1t,
                                              const float* __restrict__ ea,
                                              __half* __restrict__ eah) {
  if (blockIdx.x >= NB_HIST + 9) {
    // streaming f32 -> f16: thread handles one float4 (16B read, 8B write)
    int id = (blockIdx.x - NB_HIST - 9) * 256 + threadIdx.x;
    float4 v = ((const float4*)ea)[id];
    __half2* dst = (__half2*)eah;
    dst[2 * id + 0] = __floats2half2_rn(v.x, v.y);
    dst[2 * id + 1] = __floats2half2_rn(v.z, v.w);
    return;
  }
  if (blockIdx.x >= NB_HIST) {
    int id = (blockIdx.x - NB_HIST) * 256 + threadIdx.x;
    if (id < 36 * 64) {
      int k = id >> 6, o = id & 63;
      W1t[id] = W1[o * 36 + k];
    }
    return;
  }
  int e = blockIdx.x * 256 + threadIdx.x;
  atomicAdd(&deg[ei[NE + e]], 1);
}

__global__ __launch_bounds__(256) void k_scan1(const int* __restrict__ deg,
                                               int* __restrict__ offs,
                                               int* __restrict__ bsums) {
  __shared__ int sh[256];
  int tid = threadIdx.x;
  int i = blockIdx.x * 256 + tid;
  int v = (i < NN) ? deg[i] : 0;
  int val = v;
  sh[tid] = val;
  __syncthreads();
  for (int ofs = 1; ofs < 256; ofs <<= 1) {
    int t = (tid >= ofs) ? sh[tid - ofs] : 0;
    __syncthreads();
    val += t;
    sh[tid] = val;
    __syncthreads();
  }
  if (i < NN) offs[i] = val - v;
  if (tid == 255) bsums[blockIdx.x] = val;
}

__global__ __launch_bounds__(256) void k_scan2(int* __restrict__ bsums) {
  __shared__ int sh[256];
  int tid = threadIdx.x;
  int v = (tid < NB_SCAN) ? bsums[tid] : 0;
  int val = v;
  sh[tid] = val;
  __syncthreads();
  for (int ofs = 1; ofs < 256; ofs <<= 1) {
    int t = (tid >= ofs) ? sh[tid - ofs] : 0;
    __syncthreads();
    val += t;
    sh[tid] = val;
    __syncthreads();
  }
  if (tid < NB_SCAN) bsums[tid] = val - v;
}

__global__ __launch_bounds__(256) void k_scan3(int* __restrict__ offs,
                                               const int* __restrict__ bsums,
                                               int* __restrict__ fill) {
  int i = blockIdx.x * 256 + threadIdx.x;
  if (i < NN) {
    int v = offs[i] + bsums[blockIdx.x];
    offs[i] = v;
    fill[i] = v;
  }
}

__global__ __launch_bounds__(256) void k_scatter(const int* __restrict__ ei,
                                                 int* __restrict__ fill,
                                                 u64* __restrict__ eslist) {
  int e = blockIdx.x * 256 + threadIdx.x;
  if (e >= NE) return;
  int s = ei[e];
  int d = ei[NE + e];
  int pos = atomicAdd(&fill[d], 1);
  eslist[pos] = (u64)e | ((u64)s << 20) | ((u64)d << 40);
}

// ---------------- gather0: 16 lanes/node, f16 rows (64B), 8-row unroll ------
__global__ __launch_bounds__(256) void k_gather0(
    const __half* __restrict__ eah, const float* __restrict__ ns,
    const int* __restrict__ offs, const int* __restrict__ deg,
    const u64* __restrict__ eslist, float* __restrict__ agg_h0,
    float* __restrict__ agg_e) {
  int idx = blockIdx.x * 256 + threadIdx.x;
  int n = idx >> 4, k = idx & 15;
  if (n >= NN) return;
  int off = offs[n], dg = deg[n];
  const __half2* eh2 = (const __half2*)eah;
  float2 a0 = {0.f, 0.f}, a1 = {0.f, 0.f};
  float2 a2 = {0.f, 0.f}, a3 = {0.f, 0.f};
  float hacc = 0.f;
  int i = 0;
  for (; i + 8 <= dg; i += 8) {
    u64 p0 = eslist[off + i + 0], p1 = eslist[off + i + 1];
    u64 p2 = eslist[off + i + 2], p3 = eslist[off + i + 3];
    u64 p4 = eslist[off + i + 4], p5 = eslist[off + i + 5];
    u64 p6 = eslist[off + i + 6], p7 = eslist[off + i + 7];
    float2 v0 = __half22float2(eh2[(size_t)dec_e(p0) * 16 + k]);
    float2 v1 = __half22float2(eh2[(size_t)dec_e(p1) * 16 + k]);
    float2 v2 = __half22float2(eh2[(size_t)dec_e(p2) * 16 + k]);
    float2 v3 = __half22float2(eh2[(size_t)dec_e(p3) * 16 + k]);
    float2 v4 = __half22float2(eh2[(size_t)dec_e(p4) * 16 + k]);
    float2 v5 = __half22float2(eh2[(size_t)dec_e(p5) * 16 + k]);
    float2 v6 = __half22float2(eh2[(size_t)dec_e(p6) * 16 + k]);
    float2 v7 = __half22float2(eh2[(size_t)dec_e(p7) * 16 + k]);
    a0.x += v0.x + v4.x; a0.y += v0.y + v4.y;
    a1.x += v1.x + v5.x; a1.y += v1.y + v5.y;
    a2.x += v2.x + v6.x; a2.y += v2.y + v6.y;
    a3.x += v3.x + v7.x; a3.y += v3.y + v7.y;
    u64 ps = eslist[off + i + (k >> 1)];
    hacc += ns[(size_t)dec_s(ps) * 2 + (k & 1)];
  }
  for (; i < dg; ++i) {
    u64 p0 = eslist[off + i];
    float2 v = __half22float2(eh2[(size_t)dec_e(p0) * 16 + k]);
    a0.x += v.x; a0.y += v.y;
    if (k < 2) hacc += ns[(size_t)dec_s(p0) * 2 + k];
  }
  float2 r;
  r.x = (a0.x + a1.x) + (a2.x + a3.x);
  r.y = (a0.y + a1.y) + (a2.y + a3.y);
  ((float2*)agg_e)[(size_t)n * 16 + k] = r;
  hacc += __shfl_xor(hacc, 2, 16);
  hacc += __shfl_xor(hacc, 4, 16);
  hacc += __shfl_xor(hacc, 8, 16);
  if (k < 2) agg_h0[(size_t)n * 2 + k] = hacc;
}

// ---------------- gather1: 32-lane group/node, half2, 8-row unroll ----------
__global__ __launch_bounds__(256) void k_gather1(
    const __half* __restrict__ h1h, const int* __restrict__ offs,
    const int* __restrict__ deg, const u64* __restrict__ eslist,
    float* __restrict__ agg_h1) {
  int idx = blockIdx.x * 256 + threadIdx.x;
  int n = idx >> 5, k = idx & 31;
  if (n >= NN) return;
  int off = offs[n], dg = deg[n];
  const __half2* h2p = (const __half2*)h1h;
  float x0 = 0.f, y0 = 0.f, x1 = 0.f, y1 = 0.f;
  float x2 = 0.f, y2 = 0.f, x3 = 0.f, y3 = 0.f;
  int i = 0;
  for (; i + 8 <= dg; i += 8) {
    int s0 = dec_s(eslist[off + i + 0]), s1 = dec_s(eslist[off + i + 1]);
    int s2 = dec_s(eslist[off + i + 2]), s3 = dec_s(eslist[off + i + 3]);
    int s4 = dec_s(eslist[off + i + 4]), s5 = dec_s(eslist[off + i + 5]);
    int s6 = dec_s(eslist[off + i + 6]), s7 = dec_s(eslist[off + i + 7]);
    float2 v0 = __half22float2(h2p[(size_t)s0 * 32 + k]);
    float2 v1 = __half22float2(h2p[(size_t)s1 * 32 + k]);
    float2 v2 = __half22float2(h2p[(size_t)s2 * 32 + k]);
    float2 v3 = __half22float2(h2p[(size_t)s3 * 32 + k]);
    float2 v4 = __half22float2(h2p[(size_t)s4 * 32 + k]);
    float2 v5 = __half22float2(h2p[(size_t)s5 * 32 + k]);
    float2 v6 = __half22float2(h2p[(size_t)s6 * 32 + k]);
    float2 v7 = __half22float2(h2p[(size_t)s7 * 32 + k]);
    x0 += v0.x + v4.x; y0 += v0.y + v4.y;
    x1 += v1.x + v5.x; y1 += v1.y + v5.y;
    x2 += v2.x + v6.x; y2 += v2.y + v6.y;
    x3 += v3.x + v7.x; y3 += v3.y + v7.y;
  }
  for (; i + 2 <= dg; i += 2) {
    int s0 = dec_s(eslist[off + i]), s1 = dec_s(eslist[off + i + 1]);
    float2 v0 = __half22float2(h2p[(size_t)s0 * 32 + k]);
    float2 v1 = __half22float2(h2p[(size_t)s1 * 32 + k]);
    x0 += v0.x; y0 += v0.y;
    x1 += v1.x; y1 += v1.y;
  }
  if (i < dg) {
    float2 v0 = __half22float2(h2p[(size_t)dec_s(eslist[off + i]) * 32 + k]);
    x0 += v0.x; y0 += v0.y;
  }
  float2 r;
  r.x = (x0 + x1) + (x2 + x3);
  r.y = (y0 + y1) + (y2 + y3);
  ((float2*)agg_h1)[(size_t)n * 32 + k] = r;
}

// ---------------- node linear 1 (vector; K=36) ------------------------------
__global__ __launch_bounds__(256) void k_node_lin1(
    const float* __restrict__ ns, const int* __restrict__ deg,
    const float* __restrict__ agg_h0, const float* __restrict__ agg_e,
    const float* __restrict__ W1t, const float* __restrict__ b1,
    __half* __restrict__ h1h) {
  int idx = blockIdx.x * 256 + threadIdx.x;
  int n = idx >> 6, o = idx & 63;
  if (n >= NN) return;
  float inv = 1.0f / fmaxf((float)deg[n], 1.0f);
  float acc = b1[o], acc2 = 0.f;
  acc += ns[n * 2 + 0] * W1t[0 * 64 + o] + ns[n * 2 + 1] * W1t[1 * 64 + o];
  acc2 += agg_h0[n * 2 + 0] * inv * W1t[2 * 64 + o] +
          agg_h0[n * 2 + 1] * inv * W1t[3 * 64 + o];
#pragma unroll
  for (int k = 0; k < 32; k += 2) {
    acc += agg_e[n * 32 + k] * inv * W1t[(4 + k) * 64 + o];
    acc2 += agg_e[n * 32 + k + 1] * inv * W1t[(5 + k) * 64 + o];
  }
  h1h[n * 64 + o] = __float2half(fmaxf(acc + acc2, 0.0f));
}

// ---------------- fused lin2 + pq: MFMA, 16-node tile per wave --------------
__global__ __launch_bounds__(256) void k_lin2pq(
    const __half* __restrict__ h1h, const int* __restrict__ deg,
    const float* __restrict__ agg_h1, const float* __restrict__ agg_e,
    const float* __restrict__ W2, const float* __restrict__ b2,
    const float* __restrict__ Wc1, const float* __restrict__ bc1,
    __half* __restrict__ Pb, __half* __restrict__ Qb) {
  __shared__ float Zt[4][16 * 68];
  int tid = threadIdx.x, lane = tid & 63, wid = tid >> 6;
  int col = lane & 15, quad = lane >> 4;
  float* zl = &Zt[wid][0];
  int task = blockIdx.x * 4 + wid;
  if (task >= NN / 16) return;  // NN = 3125*16 exactly
  int nb = task * 16;
  int nrow = nb + col;
  float inv = 1.0f / fmaxf((float)deg[nrow], 1.0f);

  f32x4 zero = {0.f, 0.f, 0.f, 0.f};
  f32x4 ce[4] = {zero, zero, zero, zero};

#pragma unroll
  for (int kc = 0; kc < 5; ++kc) {
    f16x8 af;
    if (kc < 2) {
      U4 u;
      u.u = *(const uint4*)(h1h + (size_t)nrow * 64 + kc * 32 + quad * 8);
      af = u.f;
    } else if (kc < 4) {
      const float* p = agg_h1 + (size_t)nrow * 64 + (kc - 2) * 32 + quad * 8;
      float4 a0 = ((const float4*)p)[0], a1 = ((const float4*)p)[1];
      a0.x *= inv; a0.y *= inv; a0.z *= inv; a0.w *= inv;
      a1.x *= inv; a1.y *= inv; a1.z *= inv; a1.w *= inv;
      af = cvt8(a0, a1);
    } else {
      const float* p = agg_e + (size_t)nrow * 32 + quad * 8;
      float4 a0 = ((const float4*)p)[0], a1 = ((const float4*)p)[1];
      a0.x *= inv; a0.y *= inv; a0.z *= inv; a0.w *= inv;
      a1.x *= inv; a1.y *= inv; a1.z *= inv; a1.w *= inv;
      af = cvt8(a0, a1);
    }
#pragma unroll
    for (int ob = 0; ob < 4; ++ob) {
      const float* wp = W2 + (size_t)(ob * 16 + col) * 160 + kc * 32 + quad * 8;
      f16x8 bf = cvt8(((const float4*)wp)[0], ((const float4*)wp)[1]);
      ce[ob] = __builtin_amdgcn_mfma_f32_16x16x32_f16(af, bf, ce[ob], 0, 0, 0);
    }
  }
#pragma unroll
  for (int ob = 0; ob < 4; ++ob) {
    float bv = b2[ob * 16 + col];
#pragma unroll
    for (int j = 0; j < 4; ++j)
      zl[(quad * 4 + j) * 68 + ob * 16 + col] = fmaxf(ce[ob][j] + bv, 0.f);
  }

  f32x4 pacc[4] = {zero, zero, zero, zero};
  f32x4 qacc[4] = {zero, zero, zero, zero};
#pragma unroll
  for (int kc = 0; kc < 2; ++kc) {
    const float* zc = zl + col * 68 + kc * 32 + quad * 8;
    f16x8 az = cvt8(((const float4*)zc)[0], ((const float4*)zc)[1]);
#pragma unroll
    for (int ob = 0; ob < 4; ++ob) {
      const float* wa = Wc1 + (size_t)(ob * 16 + col) * 160 + kc * 32 + quad * 8;
      f16x8 ba = cvt8(((const float4*)wa)[0], ((const float4*)wa)[1]);
      pacc[ob] = __builtin_amdgcn_mfma_f32_16x16x32_f16(az, ba, pacc[ob], 0, 0, 0);
      const float* wb = wa + 64;
      f16x8 bb = cvt8(((const float4*)wb)[0], ((const float4*)wb)[1]);
      qacc[ob] = __builtin_amdgcn_mfma_f32_16x16x32_f16(az, bb, qacc[ob], 0, 0, 0);
    }
  }
  __syncthreads();
#pragma unroll
  for (int ob = 0; ob < 4; ++ob) {
    float bv = bc1[ob * 16 + col];
#pragma unroll
    for (int j = 0; j < 4; ++j) {
      int n = nb + quad * 4 + j;
      Pb[(size_t)n * 64 + ob * 16 + col] = __float2half(pacc[ob][j] + bv);
      Qb[(size_t)n * 64 + ob * 16 + col] = __float2half(qacc[ob][j]);
    }
  }
}

// ---------------- edge classifier: MFMA, CSR order, 2-deep pipeline ---------
#define CLS_BLOCKS 3125  // 12500 waves, 1 task (64 CSR slots) each

// Issue all loads (eah row, P row, Q row) for tile mt into slot regs.
#define CLS_ISSUE(S, mt)                                                      \
  {                                                                           \
    ua_##S.u = *(const uint4*)(eah + (size_t)eA[mt] * 32 + quad * 8);         \
    const __half* pr = Pb + (size_t)sA[mt] * 64 + quad * 8;                   \
    const __half* qr = Qb + (size_t)dA[mt] * 64 + quad * 8;                   \
    p0_##S.u = *(const uint4*)pr;                                             \
    p1_##S.u = *(const uint4*)(pr + 32);                                      \
    q0_##S.u = *(const uint4*)qr;                                             \
    q1_##S.u = *(const uint4*)(qr + 32);                                      \
  }

#define CLS_ASSEMBLE(uz, up, uq, c0, c1)                                      \
  {                                                                           \
    float2 pf, qf;                                                            \
    pf = __half22float2(up.h2[0]); qf = __half22float2(uq.h2[0]);             \
    uz.h2[0] = __floats2half2_rn(fmaxf(pf.x + qf.x + c0.x, 0.f),              \
                                 fmaxf(pf.y + qf.y + c0.y, 0.f));             \
    pf = __half22float2(up.h2[1]); qf = __half22float2(uq.h2[1]);             \
    uz.h2[1] = __floats2half2_rn(fmaxf(pf.x + qf.x + c0.z, 0.f),              \
                                 fmaxf(pf.y + qf.y + c0.w, 0.f));             \
    pf = __half22float2(up.h2[2]); qf = __half22float2(uq.h2[2]);             \
    uz.h2[2] = __floats2half2_rn(fmaxf(pf.x + qf.x + c1.x, 0.f),              \
                                 fmaxf(pf.y + qf.y + c1.y, 0.f));             \
    pf = __half22float2(up.h2[3]); qf = __half22float2(uq.h2[3]);             \
    uz.h2[3] = __floats2half2_rn(fmaxf(pf.x + qf.x + c1.z, 0.f),              \
                                 fmaxf(pf.y + qf.y + c1.w, 0.f));             \
  }

#define CLS_COMPUTE(S, mt)                                                    \
  {                                                                           \
    f32x4 ce0 = __builtin_amdgcn_mfma_f32_16x16x32_f16(ua_##S.f, ctF[0], zero, 0, 0, 0); \
    f32x4 ce1 = __builtin_amdgcn_mfma_f32_16x16x32_f16(ua_##S.f, ctF[1], zero, 0, 0, 0); \
    f32x4 ce2 = __builtin_amdgcn_mfma_f32_16x16x32_f16(ua_##S.f, ctF[2], zero, 0, 0, 0); \
    f32x4 ce3 = __builtin_amdgcn_mfma_f32_16x16x32_f16(ua_##S.f, ctF[3], zero, 0, 0, 0); \
    _Pragma("unroll") for (int j = 0; j < 4; ++j) {                           \
      zl[(quad * 4 + j) * 68 + 0 + col] = ce0[j];                             \
      zl[(quad * 4 + j) * 68 + 16 + col] = ce1[j];                            \
      zl[(quad * 4 + j) * 68 + 32 + col] = ce2[j];                            \
      zl[(quad * 4 + j) * 68 + 48 + col] = ce3[j];                            \
    }                                                                         \
    f32x4 tacc0 = zero, tacc1 = zero;                                         \
    {                                                                         \
      const float* zc = zl + col * 68 + quad * 8;                             \
      float4 c0 = *(const float4*)(zc);                                       \
      float4 c1 = *(const float4*)(zc + 4);                                   \
      U4 uz;                                                                  \
      CLS_ASSEMBLE(uz, p0_##S, q0_##S, c0, c1);                               \
      tacc0 = __builtin_amdgcn_mfma_f32_16x16x32_f16(uz.f, w2F[0][0], tacc0, 0, 0, 0); \
      tacc1 = __builtin_amdgcn_mfma_f32_16x16x32_f16(uz.f, w2F[1][0], tacc1, 0, 0, 0); \
    }                                                                         \
    {                                                                         \
      const float* zc = zl + col * 68 + 32 + quad * 8;                        \
      float4 c0 = *(const float4*)(zc);                                       \
      float4 c1 = *(const float4*)(zc + 4);                                   \
      U4 uz;                                                                  \
      CLS_ASSEMBLE(uz, p1_##S, q1_##S, c0, c1);                               \
      tacc0 = __builtin_amdgcn_mfma_f32_16x16x32_f16(uz.f, w2F[0][1], tacc0, 0, 0, 0); \
      tacc1 = __builtin_amdgcn_mfma_f32_16x16x32_f16(uz.f, w2F[1][1], tacc1, 0, 0, 0); \
    }                                                                         \
    float vj[4];                                                              \
    _Pragma("unroll") for (int j = 0; j < 4; ++j) {                           \
      float t0 = fmaxf(tacc0[j] + bc2v0, 0.f);                                \
      float t1 = fmaxf(tacc1[j] + bc2v1, 0.f);                                \
      vj[j] = t0 * wc3v0 + t1 * wc3v1;                                        \
    }                                                                         \
    _Pragma("unroll") for (int m = 1; m < 16; m <<= 1) {                      \
      _Pragma("unroll") for (int j = 0; j < 4; ++j)                           \
          vj[j] += __shfl_xor(vj[j], m);                                      \
    }                                                                         \
    int ej[4];                                                                \
    _Pragma("unroll") for (int j = 0; j < 4; ++j)                             \
        ej[j] = __shfl(eA[mt], quad * 4 + j);                                 \
    if (col == 0) {                                                           \
      _Pragma("unroll") for (int j = 0; j < 4; ++j)                           \
          out[ej[j]] = vj[j] + bc3v;                                          \
    }                                                                         \
  }

__global__ __launch_bounds__(256, 4) void k_edge_cls(
    const u64* __restrict__ eslist, const __half* __restrict__ eah,
    const __half* __restrict__ Pb, const __half* __restrict__ Qb,
    const float* __restrict__ Wc1, const float* __restrict__ Wc2,
    const float* __restrict__ bc2, const float* __restrict__ Wc3,
    const float* __restrict__ bc3, float* __restrict__ out) {
  __shared__ float Zt[4][16 * 68];  // single buffer: 17408 B
  int tid = threadIdx.x;
  int lane = tid & 63, wid = tid >> 6;
  int col = lane & 15, quad = lane >> 4;
  float* zl = &Zt[wid][0];

  f16x8 ctF[4];
#pragma unroll
  for (int nt = 0; nt < 4; ++nt) {
    const float* p = Wc1 + (nt * 16 + col) * 160 + 128 + quad * 8;
    ctF[nt] = cvt8(((const float4*)p)[0], ((const float4*)p)[1]);
  }
  f16x8 w2F[2][2];
#pragma unroll
  for (int nt = 0; nt < 2; ++nt)
#pragma unroll
    for (int ks = 0; ks < 2; ++ks) {
      const float* p = Wc2 + (nt * 16 + col) * 64 + ks * 32 + quad * 8;
      w2F[nt][ks] = cvt8(((const float4*)p)[0], ((const float4*)p)[1]);
    }
  float wc3v0 = Wc3[col], wc3v1 = Wc3[16 + col];
  float bc2v0 = bc2[col], bc2v1 = bc2[16 + col];
  float bc3v = bc3[0];
  f32x4 zero = {0.f, 0.f, 0.f, 0.f};

  int gw = blockIdx.x * 4 + wid;
  for (int task = gw; task < NE / 64; task += CLS_BLOCKS * 4) {
    int tb = task * 64;
    u64 vArr[4];
#pragma unroll
    for (int mt = 0; mt < 4; ++mt) vArr[mt] = eslist[tb + mt * 16 + col];
    int eA[4], sA[4], dA[4];
#pragma unroll
    for (int mt = 0; mt < 4; ++mt) {
      eA[mt] = dec_e(vArr[mt]);
      sA[mt] = dec_s(vArr[mt]);
      dA[mt] = dec_d(vArr[mt]);
    }

    // 2-deep software pipeline over the 4 tiles
    U4 ua_0, ua_1;
    U4 p0_0, p1_0, q0_0, q1_0;
    U4 p0_1, p1_1, q0_1, q1_1;

    CLS_ISSUE(0, 0);
    CLS_ISSUE(1, 1);
    CLS_COMPUTE(0, 0);
    CLS_ISSUE(0, 2);
    CLS_COMPUTE(1, 1);
    CLS_ISSUE(1, 3);
    CLS_COMPUTE(0, 2);
    CLS_COMPUTE(1, 3);
  }
}

extern "C" void kernel_launch(void* const* d_in, const int* in_sizes, int n_in,
                              void* d_out, int out_size, void* d_ws, size_t ws_size,
                              hipStream_t stream) {
  const int*   ei  = (const int*)d_in[1];
  const float* ea  = (const float*)d_in[2];
  const float* ns  = (const float*)d_in[3];
  const float* W1  = (const float*)d_in[4];
  const float* b1  = (const float*)d_in[5];
  const float* W2  = (const float*)d_in[6];
  const float* b2  = (const float*)d_in[7];
  const float* Wc1 = (const float*)d_in[8];
  const float* bc1 = (const float*)d_in[9];
  const float* Wc2 = (const float*)d_in[10];
  const float* bc2 = (const float*)d_in[11];
  const float* Wc3 = (const float*)d_in[12];
  const float* bc3 = (const float*)d_in[13];
  float* out = (float*)d_out;

  float*  ws     = (float*)d_ws;
  int*    deg    = (int*)ws;
  float*  agg_h0 = ws + (size_t)NN;
  float*  agg_e  = ws + (size_t)3 * NN;
  float*  agg_h1 = ws + (size_t)35 * NN;
  __half* h1h    = (__half*)(ws + (size_t)99 * NN);
  float*  W1t    = ws + (size_t)131 * NN;
  int*    bsums  = (int*)(W1t + 30000);
  int*    offs   = (int*)(ws + (size_t)132 * NN);
  int*    fill   = (int*)(ws + (size_t)133 * NN);
  u64*    eslist = (u64*)(ws + (size_t)134 * NN);
  __half* Pb     = (__half*)(ws + (size_t)3 * NN);   // over agg_e (same-row)
  __half* Qb     = (__half*)(ws + (size_t)99 * NN);  // over h1h (same-row)
  __half* eah    = (__half*)(ws + (size_t)227 * NN); // 12.8M floats worth

  hipMemsetAsync(deg, 0, NN * sizeof(int), stream);

  // hist + W1 transpose + ea->f16 conversion in one launch
  k_hist<<<NB_HIST + 9 + NB_CVT, 256, 0, stream>>>(ei, deg, W1, W1t, ea, eah);
  k_scan1<<<NB_SCAN, 256, 0, stream>>>(deg, offs, bsums);
  k_scan2<<<1, 256, 0, stream>>>(bsums);
  k_scan3<<<NB_SCAN, 256, 0, stream>>>(offs, bsums, fill);
  k_scatter<<<NB_HIST, 256, 0, stream>>>(ei, fill, eslist);

  k_gather0<<<(NN * 16 + 255) / 256, 256, 0, stream>>>(eah, ns, offs, deg,
                                                       eslist, agg_h0, agg_e);
  k_node_lin1<<<(NN * 64 + 255) / 256, 256, 0, stream>>>(ns, deg, agg_h0,
                                                         agg_e, W1t, b1, h1h);
  k_gather1<<<(NN * 32 + 255) / 256, 256, 0, stream>>>(h1h, offs, deg, eslist,
                                                       agg_h1);
  k_lin2pq<<<(NN / 16 + 3) / 4, 256, 0, stream>>>(h1h, deg, agg_h1, agg_e, W2,
                                                  b2, Wc1, bc1, Pb, Qb);
  k_edge_cls<<<CLS_BLOCKS, 256, 0, stream>>>(eslist, eah, Pb, Qb, Wc1, Wc2,
                                             bc2, Wc3, bc3, out);
}

// Round 18
// 260.244 us; speedup vs baseline: 1.1298x; 1.1298x over previous
//
#include <hip/hip_runtime.h>
#include <hip/hip_fp16.h>

#define NN 50000
#define NE 800000
#define NB_SCAN 196   // ceil(NN/256)
#define NB_HIST 3125  // NE/256 exactly

typedef _Float16 f16x8 __attribute__((ext_vector_type(8)));
typedef float f32x4 __attribute__((ext_vector_type(4)));
typedef unsigned long long u64;
union U4 { uint4 u; f16x8 f; __half2 h2[4]; };

__device__ inline f16x8 cvt8(float4 a0, float4 a1) {
  U4 u;
  u.h2[0] = __floats2half2_rn(a0.x, a0.y);
  u.h2[1] = __floats2half2_rn(a0.z, a0.w);
  u.h2[2] = __floats2half2_rn(a1.x, a1.y);
  u.h2[3] = __floats2half2_rn(a1.z, a1.w);
  return u.f;
}

// CSR slot encoding: e (20b) | s<<20 (17b) | d<<40 (17b)
__device__ inline int dec_e(u64 v) { return (int)(v & 0xFFFFFull); }
__device__ inline int dec_s(u64 v) { return (int)((v >> 20) & 0x1FFFFull); }
__device__ inline int dec_d(u64 v) { return (int)(v >> 40); }

// ---- workspace layout (4B units) ----
// deg i32[NN]@0 | (unused 2NN)@NN | agg_e f32[32NN]@3NN | agg_h1 f32[64NN]@35NN
// h1h f16(32NN units)@99NN | W1t@131NN(2304) bsums@131NN+30000
// offs@132NN fill@133NN | eslist u64[NE](32NN units)@134NN..166NN
// Pb f16@3NN (over agg_e, same-row RAW in lin2pq) ; Qb f16@99NN (over h1h)

// ---------------- CSR hist (+ folded W1 transpose) --------------------------
__global__ __launch_bounds__(256) void k_hist(const int* __restrict__ ei,
                                              int* __restrict__ deg,
                                              const float* __restrict__ W1,
                                              float* __restrict__ W1t) {
  if (blockIdx.x >= NB_HIST) {
    int id = (blockIdx.x - NB_HIST) * 256 + threadIdx.x;
    if (id < 36 * 64) {
      int k = id >> 6, o = id & 63;
      W1t[id] = W1[o * 36 + k];
    }
    return;
  }
  int e = blockIdx.x * 256 + threadIdx.x;
  atomicAdd(&deg[ei[NE + e]], 1);
}

__global__ __launch_bounds__(256) void k_scan1(const int* __restrict__ deg,
                                               int* __restrict__ offs,
                                               int* __restrict__ bsums) {
  __shared__ int sh[256];
  int tid = threadIdx.x;
  int i = blockIdx.x * 256 + tid;
  int v = (i < NN) ? deg[i] : 0;
  int val = v;
  sh[tid] = val;
  __syncthreads();
  for (int ofs = 1; ofs < 256; ofs <<= 1) {
    int t = (tid >= ofs) ? sh[tid - ofs] : 0;
    __syncthreads();
    val += t;
    sh[tid] = val;
    __syncthreads();
  }
  if (i < NN) offs[i] = val - v;
  if (tid == 255) bsums[blockIdx.x] = val;
}

__global__ __launch_bounds__(256) void k_scan2(int* __restrict__ bsums) {
  __shared__ int sh[256];
  int tid = threadIdx.x;
  int v = (tid < NB_SCAN) ? bsums[tid] : 0;
  int val = v;
  sh[tid] = val;
  __syncthreads();
  for (int ofs = 1; ofs < 256; ofs <<= 1) {
    int t = (tid >= ofs) ? sh[tid - ofs] : 0;
    __syncthreads();
    val += t;
    sh[tid] = val;
    __syncthreads();
  }
  if (tid < NB_SCAN) bsums[tid] = val - v;
}

__global__ __launch_bounds__(256) void k_scan3(int* __restrict__ offs,
                                               const int* __restrict__ bsums,
                                               int* __restrict__ fill) {
  int i = blockIdx.x * 256 + threadIdx.x;
  if (i < NN) {
    int v = offs[i] + bsums[blockIdx.x];
    offs[i] = v;
    fill[i] = v;
  }
}

__global__ __launch_bounds__(256) void k_scatter(const int* __restrict__ ei,
                                                 int* __restrict__ fill,
                                                 u64* __restrict__ eslist) {
  int e = blockIdx.x * 256 + threadIdx.x;
  if (e >= NE) return;
  int s = ei[e];
  int d = ei[NE + e];
  int pos = atomicAdd(&fill[d], 1);
  eslist[pos] = (u64)e | ((u64)s << 20) | ((u64)d << 40);
}

// ------- gather0 + node_lin1 fused: 16 lanes/node, float2, 8-row unroll -----
// After the gather loop, the group's agg row is staged in wave-local LDS
// (same-wave ds ordering, no barrier) and each lane computes 4 of the 64
// h1 outputs. agg_e still written to global (lin2pq reads it); agg_h0 never
// leaves the wave.
__global__ __launch_bounds__(256) void k_gather0l1(
    const float* __restrict__ ea, const float* __restrict__ ns,
    const int* __restrict__ offs, const int* __restrict__ deg,
    const u64* __restrict__ eslist, const float* __restrict__ W1t,
    const float* __restrict__ b1, float* __restrict__ agg_e,
    __half* __restrict__ h1h) {
  __shared__ float shA[16][32];  // one row per 16-lane group (16 groups/block)
  int tid = threadIdx.x;
  int idx = blockIdx.x * 256 + tid;
  int n = idx >> 4, k = idx & 15;
  if (n >= NN) return;
  int g = tid >> 4;
  int off = offs[n], dg = deg[n];
  const float2* ea2 = (const float2*)ea;
  float2 a0 = {0.f, 0.f}, a1 = {0.f, 0.f};
  float2 a2 = {0.f, 0.f}, a3 = {0.f, 0.f};
  float hacc = 0.f;
  int i = 0;
  for (; i + 8 <= dg; i += 8) {
    u64 p0 = eslist[off + i + 0], p1 = eslist[off + i + 1];
    u64 p2 = eslist[off + i + 2], p3 = eslist[off + i + 3];
    u64 p4 = eslist[off + i + 4], p5 = eslist[off + i + 5];
    u64 p6 = eslist[off + i + 6], p7 = eslist[off + i + 7];
    float2 v0 = ea2[(size_t)dec_e(p0) * 16 + k];
    float2 v1 = ea2[(size_t)dec_e(p1) * 16 + k];
    float2 v2 = ea2[(size_t)dec_e(p2) * 16 + k];
    float2 v3 = ea2[(size_t)dec_e(p3) * 16 + k];
    float2 v4 = ea2[(size_t)dec_e(p4) * 16 + k];
    float2 v5 = ea2[(size_t)dec_e(p5) * 16 + k];
    float2 v6 = ea2[(size_t)dec_e(p6) * 16 + k];
    float2 v7 = ea2[(size_t)dec_e(p7) * 16 + k];
    a0.x += v0.x + v4.x; a0.y += v0.y + v4.y;
    a1.x += v1.x + v5.x; a1.y += v1.y + v5.y;
    a2.x += v2.x + v6.x; a2.y += v2.y + v6.y;
    a3.x += v3.x + v7.x; a3.y += v3.y + v7.y;
    u64 ps = eslist[off + i + (k >> 1)];
    hacc += ns[(size_t)dec_s(ps) * 2 + (k & 1)];
  }
  for (; i < dg; ++i) {
    u64 p0 = eslist[off + i];
    float2 v = ea2[(size_t)dec_e(p0) * 16 + k];
    a0.x += v.x; a0.y += v.y;
    if (k < 2) hacc += ns[(size_t)dec_s(p0) * 2 + k];
  }
  float2 r;
  r.x = (a0.x + a1.x) + (a2.x + a3.x);
  r.y = (a0.y + a1.y) + (a2.y + a3.y);
  ((float2*)agg_e)[(size_t)n * 16 + k] = r;
  // parity reduce: even lanes -> channel0 sum, odd lanes -> channel1 sum
  hacc += __shfl_xor(hacc, 2, 16);
  hacc += __shfl_xor(hacc, 4, 16);
  hacc += __shfl_xor(hacc, 8, 16);
  float h0v = __shfl(hacc, 0, 16);
  float h1v = __shfl(hacc, 1, 16);

  // stage agg row in wave-local LDS (no barrier: producers/consumers same wave)
  shA[g][2 * k + 0] = r.x;
  shA[g][2 * k + 1] = r.y;

  // ---- lin1: each lane computes outputs o = 4k..4k+3 ----
  float inv = 1.0f / fmaxf((float)dg, 1.0f);
  float x0 = ns[(size_t)n * 2 + 0];
  float x1 = ns[(size_t)n * 2 + 1];
  float g0 = h0v * inv, g1 = h1v * inv;
  int o = 4 * k;
  float acc[4];
#pragma unroll
  for (int j = 0; j < 4; ++j) {
    acc[j] = b1[o + j] + x0 * W1t[0 * 64 + o + j] + x1 * W1t[1 * 64 + o + j] +
             g0 * W1t[2 * 64 + o + j] + g1 * W1t[3 * 64 + o + j];
  }
#pragma unroll 4
  for (int c = 0; c < 32; ++c) {
    float xv = shA[g][c] * inv;  // broadcast read
#pragma unroll
    for (int j = 0; j < 4; ++j) acc[j] += xv * W1t[(4 + c) * 64 + o + j];
  }
  __half2 w0 = __floats2half2_rn(fmaxf(acc[0], 0.f), fmaxf(acc[1], 0.f));
  __half2 w1 = __floats2half2_rn(fmaxf(acc[2], 0.f), fmaxf(acc[3], 0.f));
  __half2* dst = (__half2*)(h1h + (size_t)n * 64 + o);
  dst[0] = w0;
  dst[1] = w1;
}

// ---------------- gather1: 32-lane group/node, half2, 8-row unroll ----------
__global__ __launch_bounds__(256) void k_gather1(
    const __half* __restrict__ h1h, const int* __restrict__ offs,
    const int* __restrict__ deg, const u64* __restrict__ eslist,
    float* __restrict__ agg_h1) {
  int idx = blockIdx.x * 256 + threadIdx.x;
  int n = idx >> 5, k = idx & 31;
  if (n >= NN) return;
  int off = offs[n], dg = deg[n];
  const __half2* h2p = (const __half2*)h1h;
  float x0 = 0.f, y0 = 0.f, x1 = 0.f, y1 = 0.f;
  float x2 = 0.f, y2 = 0.f, x3 = 0.f, y3 = 0.f;
  int i = 0;
  for (; i + 8 <= dg; i += 8) {
    int s0 = dec_s(eslist[off + i + 0]), s1 = dec_s(eslist[off + i + 1]);
    int s2 = dec_s(eslist[off + i + 2]), s3 = dec_s(eslist[off + i + 3]);
    int s4 = dec_s(eslist[off + i + 4]), s5 = dec_s(eslist[off + i + 5]);
    int s6 = dec_s(eslist[off + i + 6]), s7 = dec_s(eslist[off + i + 7]);
    float2 v0 = __half22float2(h2p[(size_t)s0 * 32 + k]);
    float2 v1 = __half22float2(h2p[(size_t)s1 * 32 + k]);
    float2 v2 = __half22float2(h2p[(size_t)s2 * 32 + k]);
    float2 v3 = __half22float2(h2p[(size_t)s3 * 32 + k]);
    float2 v4 = __half22float2(h2p[(size_t)s4 * 32 + k]);
    float2 v5 = __half22float2(h2p[(size_t)s5 * 32 + k]);
    float2 v6 = __half22float2(h2p[(size_t)s6 * 32 + k]);
    float2 v7 = __half22float2(h2p[(size_t)s7 * 32 + k]);
    x0 += v0.x + v4.x; y0 += v0.y + v4.y;
    x1 += v1.x + v5.x; y1 += v1.y + v5.y;
    x2 += v2.x + v6.x; y2 += v2.y + v6.y;
    x3 += v3.x + v7.x; y3 += v3.y + v7.y;
  }
  for (; i + 2 <= dg; i += 2) {
    int s0 = dec_s(eslist[off + i]), s1 = dec_s(eslist[off + i + 1]);
    float2 v0 = __half22float2(h2p[(size_t)s0 * 32 + k]);
    float2 v1 = __half22float2(h2p[(size_t)s1 * 32 + k]);
    x0 += v0.x; y0 += v0.y;
    x1 += v1.x; y1 += v1.y;
  }
  if (i < dg) {
    float2 v0 = __half22float2(h2p[(size_t)dec_s(eslist[off + i]) * 32 + k]);
    x0 += v0.x; y0 += v0.y;
  }
  float2 r;
  r.x = (x0 + x1) + (x2 + x3);
  r.y = (y0 + y1) + (y2 + y3);
  ((float2*)agg_h1)[(size_t)n * 32 + k] = r;
}

// ---------------- fused lin2 + pq: MFMA, 16-node tile per wave --------------
__global__ __launch_bounds__(256) void k_lin2pq(
    const __half* __restrict__ h1h, const int* __restrict__ deg,
    const float* __restrict__ agg_h1, const float* __restrict__ agg_e,
    const float* __restrict__ W2, const float* __restrict__ b2,
    const float* __restrict__ Wc1, const float* __restrict__ bc1,
    __half* __restrict__ Pb, __half* __restrict__ Qb) {
  __shared__ float Zt[4][16 * 68];
  int tid = threadIdx.x, lane = tid & 63, wid = tid >> 6;
  int col = lane & 15, quad = lane >> 4;
  float* zl = &Zt[wid][0];
  int task = blockIdx.x * 4 + wid;
  if (task >= NN / 16) return;  // NN = 3125*16 exactly
  int nb = task * 16;
  int nrow = nb + col;
  float inv = 1.0f / fmaxf((float)deg[nrow], 1.0f);

  f32x4 zero = {0.f, 0.f, 0.f, 0.f};
  f32x4 ce[4] = {zero, zero, zero, zero};

#pragma unroll
  for (int kc = 0; kc < 5; ++kc) {
    f16x8 af;
    if (kc < 2) {
      U4 u;
      u.u = *(const uint4*)(h1h + (size_t)nrow * 64 + kc * 32 + quad * 8);
      af = u.f;
    } else if (kc < 4) {
      const float* p = agg_h1 + (size_t)nrow * 64 + (kc - 2) * 32 + quad * 8;
      float4 a0 = ((const float4*)p)[0], a1 = ((const float4*)p)[1];
      a0.x *= inv; a0.y *= inv; a0.z *= inv; a0.w *= inv;
      a1.x *= inv; a1.y *= inv; a1.z *= inv; a1.w *= inv;
      af = cvt8(a0, a1);
    } else {
      const float* p = agg_e + (size_t)nrow * 32 + quad * 8;
      float4 a0 = ((const float4*)p)[0], a1 = ((const float4*)p)[1];
      a0.x *= inv; a0.y *= inv; a0.z *= inv; a0.w *= inv;
      a1.x *= inv; a1.y *= inv; a1.z *= inv; a1.w *= inv;
      af = cvt8(a0, a1);
    }
#pragma unroll
    for (int ob = 0; ob < 4; ++ob) {
      const float* wp = W2 + (size_t)(ob * 16 + col) * 160 + kc * 32 + quad * 8;
      f16x8 bf = cvt8(((const float4*)wp)[0], ((const float4*)wp)[1]);
      ce[ob] = __builtin_amdgcn_mfma_f32_16x16x32_f16(af, bf, ce[ob], 0, 0, 0);
    }
  }
#pragma unroll
  for (int ob = 0; ob < 4; ++ob) {
    float bv = b2[ob * 16 + col];
#pragma unroll
    for (int j = 0; j < 4; ++j)
      zl[(quad * 4 + j) * 68 + ob * 16 + col] = fmaxf(ce[ob][j] + bv, 0.f);
  }

  f32x4 pacc[4] = {zero, zero, zero, zero};
  f32x4 qacc[4] = {zero, zero, zero, zero};
#pragma unroll
  for (int kc = 0; kc < 2; ++kc) {
    const float* zc = zl + col * 68 + kc * 32 + quad * 8;
    f16x8 az = cvt8(((const float4*)zc)[0], ((const float4*)zc)[1]);
#pragma unroll
    for (int ob = 0; ob < 4; ++ob) {
      const float* wa = Wc1 + (size_t)(ob * 16 + col) * 160 + kc * 32 + quad * 8;
      f16x8 ba = cvt8(((const float4*)wa)[0], ((const float4*)wa)[1]);
      pacc[ob] = __builtin_amdgcn_mfma_f32_16x16x32_f16(az, ba, pacc[ob], 0, 0, 0);
      const float* wb = wa + 64;
      f16x8 bb = cvt8(((const float4*)wb)[0], ((const float4*)wb)[1]);
      qacc[ob] = __builtin_amdgcn_mfma_f32_16x16x32_f16(az, bb, qacc[ob], 0, 0, 0);
    }
  }
  __syncthreads();
#pragma unroll
  for (int ob = 0; ob < 4; ++ob) {
    float bv = bc1[ob * 16 + col];
#pragma unroll
    for (int j = 0; j < 4; ++j) {
      int n = nb + quad * 4 + j;
      Pb[(size_t)n * 64 + ob * 16 + col] = __float2half(pacc[ob][j] + bv);
      Qb[(size_t)n * 64 + ob * 16 + col] = __float2half(qacc[ob][j]);
    }
  }
}

// ---------------- edge classifier: MFMA, CSR order, 2-deep pipeline ---------
#define CLS_BLOCKS 3125  // 12500 waves, 1 task (64 CSR slots) each

#define CLS_ISSUE(S, mt)                                                      \
  {                                                                           \
    const float* eap = ea + (size_t)eA[mt] * 32 + quad * 8;                   \
    a0_##S = ((const float4*)eap)[0];                                         \
    a1_##S = ((const float4*)eap)[1];                                         \
    const __half* pr = Pb + (size_t)sA[mt] * 64 + quad * 8;                   \
    const __half* qr = Qb + (size_t)dA[mt] * 64 + quad * 8;                   \
    p0_##S.u = *(const uint4*)pr;                                             \
    p1_##S.u = *(const uint4*)(pr + 32);                                      \
    q0_##S.u = *(const uint4*)qr;                                             \
    q1_##S.u = *(const uint4*)(qr + 32);                                      \
  }

#define CLS_ASSEMBLE(uz, up, uq, c0, c1)                                      \
  {                                                                           \
    float2 pf, qf;                                                            \
    pf = __half22float2(up.h2[0]); qf = __half22float2(uq.h2[0]);             \
    uz.h2[0] = __floats2half2_rn(fmaxf(pf.x + qf.x + c0.x, 0.f),              \
                                 fmaxf(pf.y + qf.y + c0.y, 0.f));             \
    pf = __half22float2(up.h2[1]); qf = __half22float2(uq.h2[1]);             \
    uz.h2[1] = __floats2half2_rn(fmaxf(pf.x + qf.x + c0.z, 0.f),              \
                                 fmaxf(pf.y + qf.y + c0.w, 0.f));             \
    pf = __half22float2(up.h2[2]); qf = __half22float2(uq.h2[2]);             \
    uz.h2[2] = __floats2half2_rn(fmaxf(pf.x + qf.x + c1.x, 0.f),              \
                                 fmaxf(pf.y + qf.y + c1.y, 0.f));             \
    pf = __half22float2(up.h2[3]); qf = __half22float2(uq.h2[3]);             \
    uz.h2[3] = __floats2half2_rn(fmaxf(pf.x + qf.x + c1.z, 0.f),              \
                                 fmaxf(pf.y + qf.y + c1.w, 0.f));             \
  }

#define CLS_COMPUTE(S, mt)                                                    \
  {                                                                           \
    f16x8 ua = cvt8(a0_##S, a1_##S);                                          \
    f32x4 ce0 = __builtin_amdgcn_mfma_f32_16x16x32_f16(ua, ctF[0], zero, 0, 0, 0); \
    f32x4 ce1 = __builtin_amdgcn_mfma_f32_16x16x32_f16(ua, ctF[1], zero, 0, 0, 0); \
    f32x4 ce2 = __builtin_amdgcn_mfma_f32_16x16x32_f16(ua, ctF[2], zero, 0, 0, 0); \
    f32x4 ce3 = __builtin_amdgcn_mfma_f32_16x16x32_f16(ua, ctF[3], zero, 0, 0, 0); \
    _Pragma("unroll") for (int j = 0; j < 4; ++j) {                           \
      zl[(quad * 4 + j) * 68 + 0 + col] = ce0[j];                             \
      zl[(quad * 4 + j) * 68 + 16 + col] = ce1[j];                            \
      zl[(quad * 4 + j) * 68 + 32 + col] = ce2[j];                            \
      zl[(quad * 4 + j) * 68 + 48 + col] = ce3[j];                            \
    }                                                                         \
    f32x4 tacc0 = zero, tacc1 = zero;                                         \
    {                                                                         \
      const float* zc = zl + col * 68 + quad * 8;                             \
      float4 c0 = *(const float4*)(zc);                                       \
      float4 c1 = *(const float4*)(zc + 4);                                   \
      U4 uz;                                                                  \
      CLS_ASSEMBLE(uz, p0_##S, q0_##S, c0, c1);                               \
      tacc0 = __builtin_amdgcn_mfma_f32_16x16x32_f16(uz.f, w2F[0][0], tacc0, 0, 0, 0); \
      tacc1 = __builtin_amdgcn_mfma_f32_16x16x32_f16(uz.f, w2F[1][0], tacc1, 0, 0, 0); \
    }                                                                         \
    {                                                                         \
      const float* zc = zl + col * 68 + 32 + quad * 8;                        \
      float4 c0 = *(const float4*)(zc);                                       \
      float4 c1 = *(const float4*)(zc + 4);                                   \
      U4 uz;                                                                  \
      CLS_ASSEMBLE(uz, p1_##S, q1_##S, c0, c1);                               \
      tacc0 = __builtin_amdgcn_mfma_f32_16x16x32_f16(uz.f, w2F[0][1], tacc0, 0, 0, 0); \
      tacc1 = __builtin_amdgcn_mfma_f32_16x16x32_f16(uz.f, w2F[1][1], tacc1, 0, 0, 0); \
    }                                                                         \
    float vj[4];                                                              \
    _Pragma("unroll") for (int j = 0; j < 4; ++j) {                           \
      float t0 = fmaxf(tacc0[j] + bc2v0, 0.f);                                \
      float t1 = fmaxf(tacc1[j] + bc2v1, 0.f);                                \
      vj[j] = t0 * wc3v0 + t1 * wc3v1;                                        \
    }                                                                         \
    _Pragma("unroll") for (int m = 1; m < 16; m <<= 1) {                      \
      _Pragma("unroll") for (int j = 0; j < 4; ++j)                           \
          vj[j] += __shfl_xor(vj[j], m);                                      \
    }                                                                         \
    int ej[4];                                                                \
    _Pragma("unroll") for (int j = 0; j < 4; ++j)                             \
        ej[j] = __shfl(eA[mt], quad * 4 + j);                                 \
    if (col == 0) {                                                           \
      _Pragma("unroll") for (int j = 0; j < 4; ++j)                           \
          out[ej[j]] = vj[j] + bc3v;                                          \
    }                                                                         \
  }

__global__ __launch_bounds__(256, 4) void k_edge_cls(
    const u64* __restrict__ eslist, const float* __restrict__ ea,
    const __half* __restrict__ Pb, const __half* __restrict__ Qb,
    const float* __restrict__ Wc1, const float* __restrict__ Wc2,
    const float* __restrict__ bc2, const float* __restrict__ Wc3,
    const float* __restrict__ bc3, float* __restrict__ out) {
  __shared__ float Zt[4][16 * 68];  // single buffer: 17408 B
  int tid = threadIdx.x;
  int lane = tid & 63, wid = tid >> 6;
  int col = lane & 15, quad = lane >> 4;
  float* zl = &Zt[wid][0];

  f16x8 ctF[4];
#pragma unroll
  for (int nt = 0; nt < 4; ++nt) {
    const float* p = Wc1 + (nt * 16 + col) * 160 + 128 + quad * 8;
    ctF[nt] = cvt8(((const float4*)p)[0], ((const float4*)p)[1]);
  }
  f16x8 w2F[2][2];
#pragma unroll
  for (int nt = 0; nt < 2; ++nt)
#pragma unroll
    for (int ks = 0; ks < 2; ++ks) {
      const float* p = Wc2 + (nt * 16 + col) * 64 + ks * 32 + quad * 8;
      w2F[nt][ks] = cvt8(((const float4*)p)[0], ((const float4*)p)[1]);
    }
  float wc3v0 = Wc3[col], wc3v1 = Wc3[16 + col];
  float bc2v0 = bc2[col], bc2v1 = bc2[16 + col];
  float bc3v = bc3[0];
  f32x4 zero = {0.f, 0.f, 0.f, 0.f};

  int gw = blockIdx.x * 4 + wid;
  for (int task = gw; task < NE / 64; task += CLS_BLOCKS * 4) {
    int tb = task * 64;
    u64 vArr[4];
#pragma unroll
    for (int mt = 0; mt < 4; ++mt) vArr[mt] = eslist[tb + mt * 16 + col];
    int eA[4], sA[4], dA[4];
#pragma unroll
    for (int mt = 0; mt < 4; ++mt) {
      eA[mt] = dec_e(vArr[mt]);
      sA[mt] = dec_s(vArr[mt]);
      dA[mt] = dec_d(vArr[mt]);
    }

    float4 a0_0, a1_0, a0_1, a1_1;
    U4 p0_0, p1_0, q0_0, q1_0;
    U4 p0_1, p1_1, q0_1, q1_1;

    CLS_ISSUE(0, 0);
    CLS_ISSUE(1, 1);
    CLS_COMPUTE(0, 0);
    CLS_ISSUE(0, 2);
    CLS_COMPUTE(1, 1);
    CLS_ISSUE(1, 3);
    CLS_COMPUTE(0, 2);
    CLS_COMPUTE(1, 3);
  }
}

extern "C" void kernel_launch(void* const* d_in, const int* in_sizes, int n_in,
                              void* d_out, int out_size, void* d_ws, size_t ws_size,
                              hipStream_t stream) {
  const int*   ei  = (const int*)d_in[1];
  const float* ea  = (const float*)d_in[2];
  const float* ns  = (const float*)d_in[3];
  const float* W1  = (const float*)d_in[4];
  const float* b1  = (const float*)d_in[5];
  const float* W2  = (const float*)d_in[6];
  const float* b2  = (const float*)d_in[7];
  const float* Wc1 = (const float*)d_in[8];
  const float* bc1 = (const float*)d_in[9];
  const float* Wc2 = (const float*)d_in[10];
  const float* bc2 = (const float*)d_in[11];
  const float* Wc3 = (const float*)d_in[12];
  const float* bc3 = (const float*)d_in[13];
  float* out = (float*)d_out;

  float*  ws     = (float*)d_ws;
  int*    deg    = (int*)ws;
  float*  agg_e  = ws + (size_t)3 * NN;
  float*  agg_h1 = ws + (size_t)35 * NN;
  __half* h1h    = (__half*)(ws + (size_t)99 * NN);
  float*  W1t    = ws + (size_t)131 * NN;
  int*    bsums  = (int*)(W1t + 30000);
  int*    offs   = (int*)(ws + (size_t)132 * NN);
  int*    fill   = (int*)(ws + (size_t)133 * NN);
  u64*    eslist = (u64*)(ws + (size_t)134 * NN);
  __half* Pb     = (__half*)(ws + (size_t)3 * NN);   // over agg_e (same-row)
  __half* Qb     = (__half*)(ws + (size_t)99 * NN);  // over h1h (same-row)

  hipMemsetAsync(deg, 0, NN * sizeof(int), stream);

  k_hist<<<NB_HIST + 9, 256, 0, stream>>>(ei, deg, W1, W1t);
  k_scan1<<<NB_SCAN, 256, 0, stream>>>(deg, offs, bsums);
  k_scan2<<<1, 256, 0, stream>>>(bsums);
  k_scan3<<<NB_SCAN, 256, 0, stream>>>(offs, bsums, fill);
  k_scatter<<<NB_HIST, 256, 0, stream>>>(ei, fill, eslist);

  k_gather0l1<<<(NN * 16 + 255) / 256, 256, 0, stream>>>(
      ea, ns, offs, deg, eslist, W1t, b1, agg_e, h1h);
  k_gather1<<<(NN * 32 + 255) / 256, 256, 0, stream>>>(h1h, offs, deg, eslist,
                                                       agg_h1);
  k_lin2pq<<<(NN / 16 + 3) / 4, 256, 0, stream>>>(h1h, deg, agg_h1, agg_e, W2,
                                                  b2, Wc1, bc1, Pb, Qb);
  k_edge_cls<<<CLS_BLOCKS, 256, 0, stream>>>(eslist, ea, Pb, Qb, Wc1, Wc2,
                                             bc2, Wc3, bc3, out);
}

// Round 19
// 258.847 us; speedup vs baseline: 1.1359x; 1.0054x over previous
//
#include <hip/hip_runtime.h>
#include <hip/hip_fp16.h>

#define NN 50000
#define NE 800000
#define NB_SCAN 196   // ceil(NN/256)
#define NB_HIST 3125  // NE/256 exactly

typedef _Float16 f16x8 __attribute__((ext_vector_type(8)));
typedef float f32x4 __attribute__((ext_vector_type(4)));
typedef unsigned long long u64;
union U4 { uint4 u; f16x8 f; __half2 h2[4]; };

__device__ inline f16x8 cvt8(float4 a0, float4 a1) {
  U4 u;
  u.h2[0] = __floats2half2_rn(a0.x, a0.y);
  u.h2[1] = __floats2half2_rn(a0.z, a0.w);
  u.h2[2] = __floats2half2_rn(a1.x, a1.y);
  u.h2[3] = __floats2half2_rn(a1.z, a1.w);
  return u.f;
}

// CSR slot encoding: e (20b) | s<<20 (17b) | d<<40 (17b)
__device__ inline int dec_e(u64 v) { return (int)(v & 0xFFFFFull); }
__device__ inline int dec_s(u64 v) { return (int)((v >> 20) & 0x1FFFFull); }
__device__ inline int dec_d(u64 v) { return (int)(v >> 40); }

// ---- workspace layout (4B units) ----
// deg i32[NN]@0 | agg_e f32[32NN]@3NN | h1h f16(32NN units)@99NN
// W1t@131NN(2304) bsums@131NN+30000 | offs@132NN fill@133NN
// eslist u64[NE](32NN units)@134NN..166NN | Qb f16(32NN units)@166NN..198NN
// Pb f16@3NN (over agg_e, same-wave same-row RAW in k_g1lin2 phase 2)

// ---------------- CSR hist (+ folded W1 transpose) --------------------------
__global__ __launch_bounds__(256) void k_hist(const int* __restrict__ ei,
                                              int* __restrict__ deg,
                                              const float* __restrict__ W1,
                                              float* __restrict__ W1t) {
  if (blockIdx.x >= NB_HIST) {
    int id = (blockIdx.x - NB_HIST) * 256 + threadIdx.x;
    if (id < 36 * 64) {
      int k = id >> 6, o = id & 63;
      W1t[id] = W1[o * 36 + k];
    }
    return;
  }
  int e = blockIdx.x * 256 + threadIdx.x;
  atomicAdd(&deg[ei[NE + e]], 1);
}

__global__ __launch_bounds__(256) void k_scan1(const int* __restrict__ deg,
                                               int* __restrict__ offs,
                                               int* __restrict__ bsums) {
  __shared__ int sh[256];
  int tid = threadIdx.x;
  int i = blockIdx.x * 256 + tid;
  int v = (i < NN) ? deg[i] : 0;
  int val = v;
  sh[tid] = val;
  __syncthreads();
  for (int ofs = 1; ofs < 256; ofs <<= 1) {
    int t = (tid >= ofs) ? sh[tid - ofs] : 0;
    __syncthreads();
    val += t;
    sh[tid] = val;
    __syncthreads();
  }
  if (i < NN) offs[i] = val - v;
  if (tid == 255) bsums[blockIdx.x] = val;
}

__global__ __launch_bounds__(256) void k_scan2(int* __restrict__ bsums) {
  __shared__ int sh[256];
  int tid = threadIdx.x;
  int v = (tid < NB_SCAN) ? bsums[tid] : 0;
  int val = v;
  sh[tid] = val;
  __syncthreads();
  for (int ofs = 1; ofs < 256; ofs <<= 1) {
    int t = (tid >= ofs) ? sh[tid - ofs] : 0;
    __syncthreads();
    val += t;
    sh[tid] = val;
    __syncthreads();
  }
  if (tid < NB_SCAN) bsums[tid] = val - v;
}

__global__ __launch_bounds__(256) void k_scan3(int* __restrict__ offs,
                                               const int* __restrict__ bsums,
                                               int* __restrict__ fill) {
  int i = blockIdx.x * 256 + threadIdx.x;
  if (i < NN) {
    int v = offs[i] + bsums[blockIdx.x];
    offs[i] = v;
    fill[i] = v;
  }
}

__global__ __launch_bounds__(256) void k_scatter(const int* __restrict__ ei,
                                                 int* __restrict__ fill,
                                                 u64* __restrict__ eslist) {
  int e = blockIdx.x * 256 + threadIdx.x;
  if (e >= NE) return;
  int s = ei[e];
  int d = ei[NE + e];
  int pos = atomicAdd(&fill[d], 1);
  eslist[pos] = (u64)e | ((u64)s << 20) | ((u64)d << 40);
}

// ------- gather0 + node_lin1 fused: 16 lanes/node, float2, 8-row unroll -----
__global__ __launch_bounds__(256) void k_gather0l1(
    const float* __restrict__ ea, const float* __restrict__ ns,
    const int* __restrict__ offs, const int* __restrict__ deg,
    const u64* __restrict__ eslist, const float* __restrict__ W1t,
    const float* __restrict__ b1, float* __restrict__ agg_e,
    __half* __restrict__ h1h) {
  __shared__ float shA[16][32];  // one row per 16-lane group
  int tid = threadIdx.x;
  int idx = blockIdx.x * 256 + tid;
  int n = idx >> 4, k = idx & 15;
  if (n >= NN) return;
  int g = tid >> 4;
  int off = offs[n], dg = deg[n];
  const float2* ea2 = (const float2*)ea;
  float2 a0 = {0.f, 0.f}, a1 = {0.f, 0.f};
  float2 a2 = {0.f, 0.f}, a3 = {0.f, 0.f};
  float hacc = 0.f;
  int i = 0;
  for (; i + 8 <= dg; i += 8) {
    u64 p0 = eslist[off + i + 0], p1 = eslist[off + i + 1];
    u64 p2 = eslist[off + i + 2], p3 = eslist[off + i + 3];
    u64 p4 = eslist[off + i + 4], p5 = eslist[off + i + 5];
    u64 p6 = eslist[off + i + 6], p7 = eslist[off + i + 7];
    float2 v0 = ea2[(size_t)dec_e(p0) * 16 + k];
    float2 v1 = ea2[(size_t)dec_e(p1) * 16 + k];
    float2 v2 = ea2[(size_t)dec_e(p2) * 16 + k];
    float2 v3 = ea2[(size_t)dec_e(p3) * 16 + k];
    float2 v4 = ea2[(size_t)dec_e(p4) * 16 + k];
    float2 v5 = ea2[(size_t)dec_e(p5) * 16 + k];
    float2 v6 = ea2[(size_t)dec_e(p6) * 16 + k];
    float2 v7 = ea2[(size_t)dec_e(p7) * 16 + k];
    a0.x += v0.x + v4.x; a0.y += v0.y + v4.y;
    a1.x += v1.x + v5.x; a1.y += v1.y + v5.y;
    a2.x += v2.x + v6.x; a2.y += v2.y + v6.y;
    a3.x += v3.x + v7.x; a3.y += v3.y + v7.y;
    u64 ps = eslist[off + i + (k >> 1)];
    hacc += ns[(size_t)dec_s(ps) * 2 + (k & 1)];
  }
  for (; i < dg; ++i) {
    u64 p0 = eslist[off + i];
    float2 v = ea2[(size_t)dec_e(p0) * 16 + k];
    a0.x += v.x; a0.y += v.y;
    if (k < 2) hacc += ns[(size_t)dec_s(p0) * 2 + k];
  }
  float2 r;
  r.x = (a0.x + a1.x) + (a2.x + a3.x);
  r.y = (a0.y + a1.y) + (a2.y + a3.y);
  ((float2*)agg_e)[(size_t)n * 16 + k] = r;
  hacc += __shfl_xor(hacc, 2, 16);
  hacc += __shfl_xor(hacc, 4, 16);
  hacc += __shfl_xor(hacc, 8, 16);
  float h0v = __shfl(hacc, 0, 16);
  float h1v = __shfl(hacc, 1, 16);

  shA[g][2 * k + 0] = r.x;
  shA[g][2 * k + 1] = r.y;

  float inv = 1.0f / fmaxf((float)dg, 1.0f);
  float x0 = ns[(size_t)n * 2 + 0];
  float x1 = ns[(size_t)n * 2 + 1];
  float g0 = h0v * inv, g1 = h1v * inv;
  int o = 4 * k;
  float acc[4];
#pragma unroll
  for (int j = 0; j < 4; ++j) {
    acc[j] = b1[o + j] + x0 * W1t[0 * 64 + o + j] + x1 * W1t[1 * 64 + o + j] +
             g0 * W1t[2 * 64 + o + j] + g1 * W1t[3 * 64 + o + j];
  }
#pragma unroll 4
  for (int c = 0; c < 32; ++c) {
    float xv = shA[g][c] * inv;
#pragma unroll
    for (int j = 0; j < 4; ++j) acc[j] += xv * W1t[(4 + c) * 64 + o + j];
  }
  __half2 w0 = __floats2half2_rn(fmaxf(acc[0], 0.f), fmaxf(acc[1], 0.f));
  __half2 w1 = __floats2half2_rn(fmaxf(acc[2], 0.f), fmaxf(acc[3], 0.f));
  __half2* dst = (__half2*)(h1h + (size_t)n * 64 + o);
  dst[0] = w0;
  dst[1] = w1;
}

// ------- fused gather1 + lin2 + pq: block = 16 nodes ------------------------
// Phase 1: 8x 32-lane groups gather h1[src] sums for the block's 16 nodes
// into LDS aggH (f32, same arithmetic as old gather1). Phase 2 (wave 0):
// MFMA lin2+pq task reading aggH from LDS. agg_h1 never touches global.
// Qb is in a FRESH region (phase-1 blocks read h1h rows of random sources,
// so Qb may no longer alias h1h). Pb/agg_e alias kept (same-wave same-row).
__global__ __launch_bounds__(256) void k_g1lin2(
    const __half* __restrict__ h1h, const int* __restrict__ deg,
    const int* __restrict__ offs, const u64* __restrict__ eslist,
    const float* __restrict__ agg_e, const float* __restrict__ W2,
    const float* __restrict__ b2, const float* __restrict__ Wc1,
    const float* __restrict__ bc1, __half* __restrict__ Pb,
    __half* __restrict__ Qb) {
  __shared__ float aggH[16][68];     // 4.35 KB (stride 68: float4-aligned)
  __shared__ __half Zth[16 * 72];    // 2.25 KB (stride 72: uint4-aligned)
  int tid = threadIdx.x;
  int nb = blockIdx.x * 16;          // NN = 3125*16 exactly
  int g = tid >> 5, k = tid & 31;
  const __half2* h2p = (const __half2*)h1h;

  // ---- phase 1: gather 16 nodes (2 per group) ----
#pragma unroll
  for (int it = 0; it < 2; ++it) {
    int li = it * 8 + g;
    int n = nb + li;
    int off = offs[n], dg = deg[n];
    float x0 = 0.f, y0 = 0.f, x1 = 0.f, y1 = 0.f;
    float x2 = 0.f, y2 = 0.f, x3 = 0.f, y3 = 0.f;
    int i = 0;
    for (; i + 8 <= dg; i += 8) {
      int s0 = dec_s(eslist[off + i + 0]), s1 = dec_s(eslist[off + i + 1]);
      int s2 = dec_s(eslist[off + i + 2]), s3 = dec_s(eslist[off + i + 3]);
      int s4 = dec_s(eslist[off + i + 4]), s5 = dec_s(eslist[off + i + 5]);
      int s6 = dec_s(eslist[off + i + 6]), s7 = dec_s(eslist[off + i + 7]);
      float2 v0 = __half22float2(h2p[(size_t)s0 * 32 + k]);
      float2 v1 = __half22float2(h2p[(size_t)s1 * 32 + k]);
      float2 v2 = __half22float2(h2p[(size_t)s2 * 32 + k]);
      float2 v3 = __half22float2(h2p[(size_t)s3 * 32 + k]);
      float2 v4 = __half22float2(h2p[(size_t)s4 * 32 + k]);
      float2 v5 = __half22float2(h2p[(size_t)s5 * 32 + k]);
      float2 v6 = __half22float2(h2p[(size_t)s6 * 32 + k]);
      float2 v7 = __half22float2(h2p[(size_t)s7 * 32 + k]);
      x0 += v0.x + v4.x; y0 += v0.y + v4.y;
      x1 += v1.x + v5.x; y1 += v1.y + v5.y;
      x2 += v2.x + v6.x; y2 += v2.y + v6.y;
      x3 += v3.x + v7.x; y3 += v3.y + v7.y;
    }
    for (; i + 2 <= dg; i += 2) {
      int s0 = dec_s(eslist[off + i]), s1 = dec_s(eslist[off + i + 1]);
      float2 v0 = __half22float2(h2p[(size_t)s0 * 32 + k]);
      float2 v1 = __half22float2(h2p[(size_t)s1 * 32 + k]);
      x0 += v0.x; y0 += v0.y;
      x1 += v1.x; y1 += v1.y;
    }
    if (i < dg) {
      float2 v0 = __half22float2(h2p[(size_t)dec_s(eslist[off + i]) * 32 + k]);
      x0 += v0.x; y0 += v0.y;
    }
    aggH[li][2 * k + 0] = (x0 + x1) + (x2 + x3);
    aggH[li][2 * k + 1] = (y0 + y1) + (y2 + y3);
  }
  __syncthreads();

  // ---- phase 2: wave 0 runs the MFMA lin2+pq task for nodes nb..nb+15 ----
  if (tid >= 64) return;
  int lane = tid, col = lane & 15, quad = lane >> 4;
  int nrow = nb + col;
  float inv = 1.0f / fmaxf((float)deg[nrow], 1.0f);

  f32x4 zero = {0.f, 0.f, 0.f, 0.f};
  f32x4 ce[4] = {zero, zero, zero, zero};

#pragma unroll
  for (int kc = 0; kc < 5; ++kc) {
    f16x8 af;
    if (kc < 2) {
      U4 u;
      u.u = *(const uint4*)(h1h + (size_t)nrow * 64 + kc * 32 + quad * 8);
      af = u.f;
    } else if (kc < 4) {
      const float* p = &aggH[col][(kc - 2) * 32 + quad * 8];
      float4 a0 = ((const float4*)p)[0], a1 = ((const float4*)p)[1];
      a0.x *= inv; a0.y *= inv; a0.z *= inv; a0.w *= inv;
      a1.x *= inv; a1.y *= inv; a1.z *= inv; a1.w *= inv;
      af = cvt8(a0, a1);
    } else {
      const float* p = agg_e + (size_t)nrow * 32 + quad * 8;
      float4 a0 = ((const float4*)p)[0], a1 = ((const float4*)p)[1];
      a0.x *= inv; a0.y *= inv; a0.z *= inv; a0.w *= inv;
      a1.x *= inv; a1.y *= inv; a1.z *= inv; a1.w *= inv;
      af = cvt8(a0, a1);
    }
#pragma unroll
    for (int ob = 0; ob < 4; ++ob) {
      const float* wp = W2 + (size_t)(ob * 16 + col) * 160 + kc * 32 + quad * 8;
      f16x8 bf = cvt8(((const float4*)wp)[0], ((const float4*)wp)[1]);
      ce[ob] = __builtin_amdgcn_mfma_f32_16x16x32_f16(af, bf, ce[ob], 0, 0, 0);
    }
  }
  // bias + relu -> f16 LDS tile (same values as fed to stage-2 MFMA before)
#pragma unroll
  for (int ob = 0; ob < 4; ++ob) {
    float bv = b2[ob * 16 + col];
#pragma unroll
    for (int j = 0; j < 4; ++j)
      Zth[(quad * 4 + j) * 72 + ob * 16 + col] =
          __float2half(fmaxf(ce[ob][j] + bv, 0.f));
  }

  f32x4 pacc[4] = {zero, zero, zero, zero};
  f32x4 qacc[4] = {zero, zero, zero, zero};
#pragma unroll
  for (int kc = 0; kc < 2; ++kc) {
    U4 uz;
    uz.u = *(const uint4*)(&Zth[col * 72 + kc * 32 + quad * 8]);
    f16x8 az = uz.f;
#pragma unroll
    for (int ob = 0; ob < 4; ++ob) {
      const float* wa = Wc1 + (size_t)(ob * 16 + col) * 160 + kc * 32 + quad * 8;
      f16x8 ba = cvt8(((const float4*)wa)[0], ((const float4*)wa)[1]);
      pacc[ob] = __builtin_amdgcn_mfma_f32_16x16x32_f16(az, ba, pacc[ob], 0, 0, 0);
      const float* wb = wa + 64;
      f16x8 bb = cvt8(((const float4*)wb)[0], ((const float4*)wb)[1]);
      qacc[ob] = __builtin_amdgcn_mfma_f32_16x16x32_f16(az, bb, qacc[ob], 0, 0, 0);
    }
  }
#pragma unroll
  for (int ob = 0; ob < 4; ++ob) {
    float bv = bc1[ob * 16 + col];
#pragma unroll
    for (int j = 0; j < 4; ++j) {
      int n = nb + quad * 4 + j;
      Pb[(size_t)n * 64 + ob * 16 + col] = __float2half(pacc[ob][j] + bv);
      Qb[(size_t)n * 64 + ob * 16 + col] = __float2half(qacc[ob][j]);
    }
  }
}

// ---------------- edge classifier: MFMA, CSR order, 2-deep pipeline ---------
#define CLS_BLOCKS 3125  // 12500 waves, 1 task (64 CSR slots) each

#define CLS_ISSUE(S, mt)                                                      \
  {                                                                           \
    const float* eap = ea + (size_t)eA[mt] * 32 + quad * 8;                   \
    a0_##S = ((const float4*)eap)[0];                                         \
    a1_##S = ((const float4*)eap)[1];                                         \
    const __half* pr = Pb + (size_t)sA[mt] * 64 + quad * 8;                   \
    const __half* qr = Qb + (size_t)dA[mt] * 64 + quad * 8;                   \
    p0_##S.u = *(const uint4*)pr;                                             \
    p1_##S.u = *(const uint4*)(pr + 32);                                      \
    q0_##S.u = *(const uint4*)qr;                                             \
    q1_##S.u = *(const uint4*)(qr + 32);                                      \
  }

#define CLS_ASSEMBLE(uz, up, uq, c0, c1)                                      \
  {                                                                           \
    float2 pf, qf;                                                            \
    pf = __half22float2(up.h2[0]); qf = __half22float2(uq.h2[0]);             \
    uz.h2[0] = __floats2half2_rn(fmaxf(pf.x + qf.x + c0.x, 0.f),              \
                                 fmaxf(pf.y + qf.y + c0.y, 0.f));             \
    pf = __half22float2(up.h2[1]); qf = __half22float2(uq.h2[1]);             \
    uz.h2[1] = __floats2half2_rn(fmaxf(pf.x + qf.x + c0.z, 0.f),              \
                                 fmaxf(pf.y + qf.y + c0.w, 0.f));             \
    pf = __half22float2(up.h2[2]); qf = __half22float2(uq.h2[2]);             \
    uz.h2[2] = __floats2half2_rn(fmaxf(pf.x + qf.x + c1.x, 0.f),              \
                                 fmaxf(pf.y + qf.y + c1.y, 0.f));             \
    pf = __half22float2(up.h2[3]); qf = __half22float2(uq.h2[3]);             \
    uz.h2[3] = __floats2half2_rn(fmaxf(pf.x + qf.x + c1.z, 0.f),              \
                                 fmaxf(pf.y + qf.y + c1.w, 0.f));             \
  }

#define CLS_COMPUTE(S, mt)                                                    \
  {                                                                           \
    f16x8 ua = cvt8(a0_##S, a1_##S);                                          \
    f32x4 ce0 = __builtin_amdgcn_mfma_f32_16x16x32_f16(ua, ctF[0], zero, 0, 0, 0); \
    f32x4 ce1 = __builtin_amdgcn_mfma_f32_16x16x32_f16(ua, ctF[1], zero, 0, 0, 0); \
    f32x4 ce2 = __builtin_amdgcn_mfma_f32_16x16x32_f16(ua, ctF[2], zero, 0, 0, 0); \
    f32x4 ce3 = __builtin_amdgcn_mfma_f32_16x16x32_f16(ua, ctF[3], zero, 0, 0, 0); \
    _Pragma("unroll") for (int j = 0; j < 4; ++j) {                           \
      zl[(quad * 4 + j) * 68 + 0 + col] = ce0[j];                             \
      zl[(quad * 4 + j) * 68 + 16 + col] = ce1[j];                            \
      zl[(quad * 4 + j) * 68 + 32 + col] = ce2[j];                            \
      zl[(quad * 4 + j) * 68 + 48 + col] = ce3[j];                            \
    }                                                                         \
    f32x4 tacc0 = zero, tacc1 = zero;                                         \
    {                                                                         \
      const float* zc = zl + col * 68 + quad * 8;                             \
      float4 c0 = *(const float4*)(zc);                                       \
      float4 c1 = *(const float4*)(zc + 4);                                   \
      U4 uz;                                                                  \
      CLS_ASSEMBLE(uz, p0_##S, q0_##S, c0, c1);                               \
      tacc0 = __builtin_amdgcn_mfma_f32_16x16x32_f16(uz.f, w2F[0][0], tacc0, 0, 0, 0); \
      tacc1 = __builtin_amdgcn_mfma_f32_16x16x32_f16(uz.f, w2F[1][0], tacc1, 0, 0, 0); \
    }                                                                         \
    {                                                                         \
      const float* zc = zl + col * 68 + 32 + quad * 8;                        \
      float4 c0 = *(const float4*)(zc);                                       \
      float4 c1 = *(const float4*)(zc + 4);                                   \
      U4 uz;                                                                  \
      CLS_ASSEMBLE(uz, p1_##S, q1_##S, c0, c1);                               \
      tacc0 = __builtin_amdgcn_mfma_f32_16x16x32_f16(uz.f, w2F[0][1], tacc0, 0, 0, 0); \
      tacc1 = __builtin_amdgcn_mfma_f32_16x16x32_f16(uz.f, w2F[1][1], tacc1, 0, 0, 0); \
    }                                                                         \
    float vj[4];                                                              \
    _Pragma("unroll") for (int j = 0; j < 4; ++j) {                           \
      float t0 = fmaxf(tacc0[j] + bc2v0, 0.f);                                \
      float t1 = fmaxf(tacc1[j] + bc2v1, 0.f);                                \
      vj[j] = t0 * wc3v0 + t1 * wc3v1;                                        \
    }                                                                         \
    _Pragma("unroll") for (int m = 1; m < 16; m <<= 1) {                      \
      _Pragma("unroll") for (int j = 0; j < 4; ++j)                           \
          vj[j] += __shfl_xor(vj[j], m);                                      \
    }                                                                         \
    int ej[4];                                                                \
    _Pragma("unroll") for (int j = 0; j < 4; ++j)                             \
        ej[j] = __shfl(eA[mt], quad * 4 + j);                                 \
    if (col == 0) {                                                           \
      _Pragma("unroll") for (int j = 0; j < 4; ++j)                           \
          out[ej[j]] = vj[j] + bc3v;                                          \
    }                                                                         \
  }

__global__ __launch_bounds__(256, 4) void k_edge_cls(
    const u64* __restrict__ eslist, const float* __restrict__ ea,
    const __half* __restrict__ Pb, const __half* __restrict__ Qb,
    const float* __restrict__ Wc1, const float* __restrict__ Wc2,
    const float* __restrict__ bc2, const float* __restrict__ Wc3,
    const float* __restrict__ bc3, float* __restrict__ out) {
  __shared__ float Zt[4][16 * 68];  // single buffer: 17408 B
  int tid = threadIdx.x;
  int lane = tid & 63, wid = tid >> 6;
  int col = lane & 15, quad = lane >> 4;
  float* zl = &Zt[wid][0];

  f16x8 ctF[4];
#pragma unroll
  for (int nt = 0; nt < 4; ++nt) {
    const float* p = Wc1 + (nt * 16 + col) * 160 + 128 + quad * 8;
    ctF[nt] = cvt8(((const float4*)p)[0], ((const float4*)p)[1]);
  }
  f16x8 w2F[2][2];
#pragma unroll
  for (int nt = 0; nt < 2; ++nt)
#pragma unroll
    for (int ks = 0; ks < 2; ++ks) {
      const float* p = Wc2 + (nt * 16 + col) * 64 + ks * 32 + quad * 8;
      w2F[nt][ks] = cvt8(((const float4*)p)[0], ((const float4*)p)[1]);
    }
  float wc3v0 = Wc3[col], wc3v1 = Wc3[16 + col];
  float bc2v0 = bc2[col], bc2v1 = bc2[16 + col];
  float bc3v = bc3[0];
  f32x4 zero = {0.f, 0.f, 0.f, 0.f};

  int gw = blockIdx.x * 4 + wid;
  for (int task = gw; task < NE / 64; task += CLS_BLOCKS * 4) {
    int tb = task * 64;
    u64 vArr[4];
#pragma unroll
    for (int mt = 0; mt < 4; ++mt) vArr[mt] = eslist[tb + mt * 16 + col];
    int eA[4], sA[4], dA[4];
#pragma unroll
    for (int mt = 0; mt < 4; ++mt) {
      eA[mt] = dec_e(vArr[mt]);
      sA[mt] = dec_s(vArr[mt]);
      dA[mt] = dec_d(vArr[mt]);
    }

    float4 a0_0, a1_0, a0_1, a1_1;
    U4 p0_0, p1_0, q0_0, q1_0;
    U4 p0_1, p1_1, q0_1, q1_1;

    CLS_ISSUE(0, 0);
    CLS_ISSUE(1, 1);
    CLS_COMPUTE(0, 0);
    CLS_ISSUE(0, 2);
    CLS_COMPUTE(1, 1);
    CLS_ISSUE(1, 3);
    CLS_COMPUTE(0, 2);
    CLS_COMPUTE(1, 3);
  }
}

extern "C" void kernel_launch(void* const* d_in, const int* in_sizes, int n_in,
                              void* d_out, int out_size, void* d_ws, size_t ws_size,
                              hipStream_t stream) {
  const int*   ei  = (const int*)d_in[1];
  const float* ea  = (const float*)d_in[2];
  const float* ns  = (const float*)d_in[3];
  const float* W1  = (const float*)d_in[4];
  const float* b1  = (const float*)d_in[5];
  const float* W2  = (const float*)d_in[6];
  const float* b2  = (const float*)d_in[7];
  const float* Wc1 = (const float*)d_in[8];
  const float* bc1 = (const float*)d_in[9];
  const float* Wc2 = (const float*)d_in[10];
  const float* bc2 = (const float*)d_in[11];
  const float* Wc3 = (const float*)d_in[12];
  const float* bc3 = (const float*)d_in[13];
  float* out = (float*)d_out;

  float*  ws     = (float*)d_ws;
  int*    deg    = (int*)ws;
  float*  agg_e  = ws + (size_t)3 * NN;
  __half* h1h    = (__half*)(ws + (size_t)99 * NN);
  float*  W1t    = ws + (size_t)131 * NN;
  int*    bsums  = (int*)(W1t + 30000);
  int*    offs   = (int*)(ws + (size_t)132 * NN);
  int*    fill   = (int*)(ws + (size_t)133 * NN);
  u64*    eslist = (u64*)(ws + (size_t)134 * NN);
  __half* Pb     = (__half*)(ws + (size_t)3 * NN);    // over agg_e (same-row)
  __half* Qb     = (__half*)(ws + (size_t)166 * NN);  // fresh region ->198NN

  hipMemsetAsync(deg, 0, NN * sizeof(int), stream);

  k_hist<<<NB_HIST + 9, 256, 0, stream>>>(ei, deg, W1, W1t);
  k_scan1<<<NB_SCAN, 256, 0, stream>>>(deg, offs, bsums);
  k_scan2<<<1, 256, 0, stream>>>(bsums);
  k_scan3<<<NB_SCAN, 256, 0, stream>>>(offs, bsums, fill);
  k_scatter<<<NB_HIST, 256, 0, stream>>>(ei, fill, eslist);

  k_gather0l1<<<(NN * 16 + 255) / 256, 256, 0, stream>>>(
      ea, ns, offs, deg, eslist, W1t, b1, agg_e, h1h);
  k_g1lin2<<<NN / 16, 256, 0, stream>>>(h1h, deg, offs, eslist, agg_e, W2, b2,
                                        Wc1, bc1, Pb, Qb);
  k_edge_cls<<<CLS_BLOCKS, 256, 0, stream>>>(eslist, ea, Pb, Qb, Wc1, Wc2,
                                             bc2, Wc3, bc3, out);
}